// Round 1
// baseline (639.376 us; speedup 1.0000x reference)
//
#include <hip/hip_runtime.h>
#include <hip/hip_bf16.h>

typedef __bf16 bf16;
typedef __bf16 bf16x8 __attribute__((ext_vector_type(8)));
typedef __bf16 bf16x4 __attribute__((ext_vector_type(4)));
typedef float f32x4 __attribute__((ext_vector_type(4)));

#define DM 2048
#define LL 2048
#define NB 2
#define NH 16
#define DH 128

__device__ __forceinline__ void gload_lds16(const void* g, void* l) {
  auto gp = (__attribute__((address_space(1))) void*)(const_cast<void*>(g));
  auto lp = (__attribute__((address_space(3))) void*)l;
  __builtin_amdgcn_global_load_lds(gp, lp, 16, 0, 0);
}

// ---------------- convert f32 -> bf16 (x + 4 weights) ----------------
__global__ __launch_bounds__(256) void convert_kernel(
    const float* __restrict__ x, const float* __restrict__ wq,
    const float* __restrict__ wk, const float* __restrict__ wv,
    const float* __restrict__ wo,
    bf16* __restrict__ xb, bf16* __restrict__ wqb, bf16* __restrict__ wkb,
    bf16* __restrict__ wvb, bf16* __restrict__ wob) {
  int i4 = blockIdx.x * 256 + threadIdx.x;  // float4 index, total 6291456
  const float* src;
  bf16* dst;
  int off;
  if (i4 < 2097152) {
    src = x; dst = xb; off = i4;
  } else {
    int t = i4 - 2097152;
    int a = t >> 20;
    off = t & 1048575;
    src = (a == 0) ? wq : (a == 1) ? wk : (a == 2) ? wv : wo;
    dst = (a == 0) ? wqb : (a == 1) ? wkb : (a == 2) ? wvb : wob;
  }
  float4 v = ((const float4*)src)[off];
  bf16x4 o = {(bf16)v.x, (bf16)v.y, (bf16)v.z, (bf16)v.w};
  ((bf16x4*)dst)[off] = o;
}

// ---------------- rope cos/sin table [L][64] ----------------
__global__ __launch_bounds__(256) void rope_table_kernel(float2* __restrict__ cs) {
  int idx = blockIdx.x * 256 + threadIdx.x;  // < 131072
  int pos = idx >> 6, i = idx & 63;
  float inv = powf(10000.0f, -(float)(2 * i) / 128.0f);
  float f = (float)pos * inv;
  cs[idx] = make_float2(cosf(f), sinf(f));
}

// ---------------- GEMM: C = A @ W^T (A: rows x 2048 bf16, W: 2048 x 2048 row-major = B^T) ----------------
// MODE 0: z selects Wq/Wk/Wv; epilogue RoPE(Q,K)->head-major, V->VT.
// MODE 1: W=Wo; epilogue writes f32 Cout.
template <int MODE>
__global__ __launch_bounds__(256) void gemm_kernel(
    const bf16* __restrict__ A, const bf16* __restrict__ B0,
    const bf16* __restrict__ B1, const bf16* __restrict__ B2,
    bf16* __restrict__ Qh, bf16* __restrict__ Kh, bf16* __restrict__ VT,
    float* __restrict__ Cout, const int* __restrict__ positions,
    const float2* __restrict__ cs) {
  __shared__ __align__(16) bf16 As[128 * 32];
  __shared__ __align__(16) bf16 Bs[128 * 32];
  const int tid = threadIdx.x;
  const int lane = tid & 63;
  const int w = tid >> 6;
  const int wr = w >> 1, wc = w & 1;
  const int lr = lane & 15, lg = lane >> 4;
  const int brow = blockIdx.x * 128;
  const int bcol = blockIdx.y * 128;
  const int z = (MODE == 0) ? (int)blockIdx.z : 0;
  const bf16* Bt = (MODE == 1) ? B0 : (z == 0 ? B0 : (z == 1 ? B1 : B2));

  f32x4 acc[4][4];
#pragma unroll
  for (int m = 0; m < 4; ++m)
#pragma unroll
    for (int n = 0; n < 4; ++n) acc[m][n] = (f32x4){0.f, 0.f, 0.f, 0.f};

  for (int kt = 0; kt < DM / 32; ++kt) {
    __syncthreads();
#pragma unroll
    for (int p = 0; p < 2; ++p) {
      int slot = p * 256 + tid;
      int row = slot >> 2, kq = slot & 3;
      gload_lds16(A + (size_t)(brow + row) * DM + kt * 32 + kq * 8,
                  As + (size_t)(p * 256 + w * 64) * 8);
      gload_lds16(Bt + (size_t)(bcol + row) * DM + kt * 32 + kq * 8,
                  Bs + (size_t)(p * 256 + w * 64) * 8);
    }
    __syncthreads();
    bf16x8 afr[4], bfr[4];
#pragma unroll
    for (int m = 0; m < 4; ++m)
      afr[m] = *(const bf16x8*)(As + (wr * 64 + m * 16 + lr) * 32 + lg * 8);
#pragma unroll
    for (int n = 0; n < 4; ++n)
      bfr[n] = *(const bf16x8*)(Bs + (wc * 64 + n * 16 + lr) * 32 + lg * 8);
#pragma unroll
    for (int m = 0; m < 4; ++m)
#pragma unroll
      for (int n = 0; n < 4; ++n)
        acc[m][n] = __builtin_amdgcn_mfma_f32_16x16x32_bf16(afr[m], bfr[n],
                                                            acc[m][n], 0, 0, 0);
  }

  if (MODE == 1) {
#pragma unroll
    for (int m = 0; m < 4; ++m)
#pragma unroll
      for (int r = 0; r < 4; ++r) {
        int gr = brow + wr * 64 + m * 16 + lg * 4 + r;
#pragma unroll
        for (int n = 0; n < 4; ++n) {
          int j = bcol + wc * 64 + n * 16 + lr;
          Cout[(size_t)gr * DM + j] = acc[m][n][r];
        }
      }
  } else if (z < 2) {
    bf16* Dst = (z == 0) ? Qh : Kh;
#pragma unroll
    for (int m = 0; m < 4; ++m)
#pragma unroll
      for (int r = 0; r < 4; ++r) {
        int gr = brow + wr * 64 + m * 16 + lg * 4 + r;
        int b = gr >> 11, l = gr & (LL - 1);
        int pos = positions[gr];
#pragma unroll
        for (int n = 0; n < 4; ++n) {
          int j = bcol + wc * 64 + n * 16 + lr;
          float v = acc[m][n][r];
          float part = __shfl_xor(v, 1);
          int d = j & 127;
          float2 csv = cs[pos * 64 + (d >> 1)];
          float res = (j & 1) ? (part * csv.y + v * csv.x)
                              : (v * csv.x - part * csv.y);
          Dst[((size_t)(b * NH + (j >> 7)) * LL + l) * DH + d] = (bf16)res;
        }
      }
  } else {
    // V -> VT[bh][d][l]
#pragma unroll
    for (int m = 0; m < 4; ++m) {
      int gr0 = brow + wr * 64 + m * 16 + lg * 4;
      int b = gr0 >> 11, l0 = gr0 & (LL - 1);
#pragma unroll
      for (int n = 0; n < 4; ++n) {
        int j = bcol + wc * 64 + n * 16 + lr;
        int d = j & 127, h = j >> 7;
        bf16x4 o = {(bf16)acc[m][n][0], (bf16)acc[m][n][1], (bf16)acc[m][n][2],
                    (bf16)acc[m][n][3]};
        *(bf16x4*)(VT + ((size_t)(b * NH + h) * DH + d) * LL + l0) = o;
      }
    }
  }
}

// ---------------- causal flash attention ----------------
// grid: (L/64, B*H). block 256 = 4 waves; wave w owns 16 q rows.
__global__ __launch_bounds__(256) void attn_kernel(const bf16* __restrict__ Qh,
                                                   const bf16* __restrict__ Kh,
                                                   const bf16* __restrict__ VT,
                                                   bf16* __restrict__ AO) {
  __shared__ __align__(16) bf16 Ks[32 * 128];
  __shared__ __align__(16) bf16 VTs[128 * 32];
  __shared__ __align__(16) bf16 Ps[4][16 * 32];
  const int tid = threadIdx.x;
  const int lane = tid & 63;
  const int w = tid >> 6;
  const int lr = lane & 15, lg = lane >> 4;
  const int bh = blockIdx.y;
  const int q0 = blockIdx.x * 64;
  const int qr0 = q0 + w * 16;
  const bf16* Qb = Qh + (size_t)bh * LL * DH;
  const bf16* Kb = Kh + (size_t)bh * LL * DH;
  const bf16* Vb = VT + (size_t)bh * DH * LL;

  bf16x8 qf[4];
#pragma unroll
  for (int dk = 0; dk < 4; ++dk)
    qf[dk] = *(const bf16x8*)(Qb + (size_t)(qr0 + lr) * DH + dk * 32 + lg * 8);

  float mx[4], ssum[4];
  f32x4 oacc[8];
#pragma unroll
  for (int r = 0; r < 4; ++r) {
    mx[r] = -1e30f;
    ssum[r] = 0.f;
  }
#pragma unroll
  for (int f = 0; f < 8; ++f) oacc[f] = (f32x4){0.f, 0.f, 0.f, 0.f};

  const float scale = 0.08838834764831845f;  // 1/sqrt(128)
  const int kvend = q0 + 64;
  for (int kv0 = 0; kv0 < kvend; kv0 += 32) {
    __syncthreads();
#pragma unroll
    for (int p = 0; p < 2; ++p) {
      int slot = p * 256 + tid;
      gload_lds16(Kb + (size_t)(kv0 + (slot >> 4)) * DH + (slot & 15) * 8,
                  Ks + (size_t)(p * 256 + w * 64) * 8);
      gload_lds16(Vb + (size_t)(slot >> 2) * LL + kv0 + (slot & 3) * 8,
                  VTs + (size_t)(p * 256 + w * 64) * 8);
    }
    __syncthreads();
    if (kv0 <= qr0 + 15) {
      f32x4 s[2];
      s[0] = (f32x4){0.f, 0.f, 0.f, 0.f};
      s[1] = (f32x4){0.f, 0.f, 0.f, 0.f};
#pragma unroll
      for (int n = 0; n < 2; ++n)
#pragma unroll
        for (int dk = 0; dk < 4; ++dk) {
          bf16x8 kf = *(const bf16x8*)(Ks + (n * 16 + lr) * 128 + dk * 32 + lg * 8);
          s[n] = __builtin_amdgcn_mfma_f32_16x16x32_bf16(qf[dk], kf, s[n], 0, 0, 0);
        }
#pragma unroll
      for (int n = 0; n < 2; ++n)
#pragma unroll
        for (int r = 0; r < 4; ++r) {
          int c = kv0 + n * 16 + lr;
          int q = qr0 + lg * 4 + r;
          float v = s[n][r] * scale;
          s[n][r] = (c > q) ? -1e30f : v;
        }
      float al[4];
#pragma unroll
      for (int r = 0; r < 4; ++r) {
        float tm = fmaxf(s[0][r], s[1][r]);
        tm = fmaxf(tm, __shfl_xor(tm, 1));
        tm = fmaxf(tm, __shfl_xor(tm, 2));
        tm = fmaxf(tm, __shfl_xor(tm, 4));
        tm = fmaxf(tm, __shfl_xor(tm, 8));
        float mn = fmaxf(mx[r], tm);
        al[r] = __expf(mx[r] - mn);
        mx[r] = mn;
        s[0][r] = __expf(s[0][r] - mn);
        s[1][r] = __expf(s[1][r] - mn);
        float t = s[0][r] + s[1][r];
        t += __shfl_xor(t, 1);
        t += __shfl_xor(t, 2);
        t += __shfl_xor(t, 4);
        t += __shfl_xor(t, 8);
        ssum[r] = ssum[r] * al[r] + t;
      }
#pragma unroll
      for (int f = 0; f < 8; ++f)
#pragma unroll
        for (int r = 0; r < 4; ++r) oacc[f][r] *= al[r];
      // P -> LDS (D-layout -> A-layout transpose through memory)
      bf16* pw = &Ps[w][0];
#pragma unroll
      for (int n = 0; n < 2; ++n)
#pragma unroll
        for (int r = 0; r < 4; ++r)
          pw[(lg * 4 + r) * 32 + n * 16 + lr] = (bf16)s[n][r];
      asm volatile("s_waitcnt lgkmcnt(0)" ::: "memory");
      bf16x8 pf = *(const bf16x8*)(pw + lr * 32 + lg * 8);
#pragma unroll
      for (int f = 0; f < 8; ++f) {
        bf16x8 vf = *(const bf16x8*)(VTs + (f * 16 + lr) * 32 + lg * 8);
        oacc[f] = __builtin_amdgcn_mfma_f32_16x16x32_bf16(pf, vf, oacc[f], 0, 0, 0);
      }
    }
  }
  const int b = bh >> 4, h = bh & 15;
#pragma unroll
  for (int f = 0; f < 8; ++f)
#pragma unroll
    for (int r = 0; r < 4; ++r) {
      int q = qr0 + lg * 4 + r;
      float val = oacc[f][r] / ssum[r];
      AO[((size_t)(b * LL + q)) * DM + h * DH + f * 16 + lr] = (bf16)val;
    }
}

extern "C" void kernel_launch(void* const* d_in, const int* in_sizes, int n_in,
                              void* d_out, int out_size, void* d_ws,
                              size_t ws_size, hipStream_t stream) {
  const float* x = (const float*)d_in[0];
  const int* positions = (const int*)d_in[1];
  const float* Wq = (const float*)d_in[2];
  const float* Wk = (const float*)d_in[3];
  const float* Wv = (const float*)d_in[4];
  const float* Wo = (const float*)d_in[5];
  float* out = (float*)d_out;
  char* ws = (char*)d_ws;
  const size_t MB = (size_t)1 << 20;
  bf16* xb = (bf16*)(ws + 0 * MB);     // 16 MB
  bf16* wqb = (bf16*)(ws + 16 * MB);   // 8 MB
  bf16* wkb = (bf16*)(ws + 24 * MB);   // 8 MB
  bf16* wvb = (bf16*)(ws + 32 * MB);   // 8 MB
  bf16* wob = (bf16*)(ws + 40 * MB);   // 8 MB
  bf16* Qh = (bf16*)(ws + 48 * MB);    // 16 MB
  bf16* Kh = (bf16*)(ws + 64 * MB);    // 16 MB
  bf16* VTb = (bf16*)(ws + 80 * MB);   // 16 MB
  bf16* AO = (bf16*)(ws + 96 * MB);    // 16 MB
  float2* cs = (float2*)(ws + 112 * MB);  // 1 MB

  convert_kernel<<<dim3(24576), dim3(256), 0, stream>>>(
      x, Wq, Wk, Wv, Wo, xb, wqb, wkb, wvb, wob);
  rope_table_kernel<<<dim3(512), dim3(256), 0, stream>>>(cs);
  gemm_kernel<0><<<dim3(32, 16, 3), dim3(256), 0, stream>>>(
      xb, wqb, wkb, wvb, Qh, Kh, VTb, nullptr, positions, cs);
  attn_kernel<<<dim3(32, 32), dim3(256), 0, stream>>>(Qh, Kh, VTb, AO);
  gemm_kernel<1><<<dim3(32, 16, 1), dim3(256), 0, stream>>>(
      AO, wob, nullptr, nullptr, nullptr, nullptr, nullptr, out, nullptr,
      nullptr);
}

// Round 2
// 450.791 us; speedup vs baseline: 1.4183x; 1.4183x over previous
//
#include <hip/hip_runtime.h>
#include <hip/hip_bf16.h>

typedef __bf16 bf16;
typedef __bf16 bf16x8 __attribute__((ext_vector_type(8)));
typedef __bf16 bf16x4 __attribute__((ext_vector_type(4)));
typedef float f32x4 __attribute__((ext_vector_type(4)));

#define DM 2048
#define LL 2048
#define NB 2
#define NH 16
#define DH 128

__device__ __forceinline__ void gload_lds16(const void* g, void* l) {
  auto gp = (__attribute__((address_space(1))) void*)(const_cast<void*>(g));
  auto lp = (__attribute__((address_space(3))) void*)l;
  __builtin_amdgcn_global_load_lds(gp, lp, 16, 0, 0);
}

// ---------------- convert f32 -> bf16 (x + 4 weights) ----------------
__global__ __launch_bounds__(256) void convert_kernel(
    const float* __restrict__ x, const float* __restrict__ wq,
    const float* __restrict__ wk, const float* __restrict__ wv,
    const float* __restrict__ wo,
    bf16* __restrict__ xb, bf16* __restrict__ wqb, bf16* __restrict__ wkb,
    bf16* __restrict__ wvb, bf16* __restrict__ wob) {
  int i4 = blockIdx.x * 256 + threadIdx.x;  // float4 index, total 6291456
  const float* src;
  bf16* dst;
  int off;
  if (i4 < 2097152) {
    src = x; dst = xb; off = i4;
  } else {
    int t = i4 - 2097152;
    int a = t >> 20;
    off = t & 1048575;
    src = (a == 0) ? wq : (a == 1) ? wk : (a == 2) ? wv : wo;
    dst = (a == 0) ? wqb : (a == 1) ? wkb : (a == 2) ? wvb : wob;
  }
  float4 v = ((const float4*)src)[off];
  bf16x4 o = {(bf16)v.x, (bf16)v.y, (bf16)v.z, (bf16)v.w};
  ((bf16x4*)dst)[off] = o;
}

// ---------------- rope cos/sin table [L][64] ----------------
__global__ __launch_bounds__(256) void rope_table_kernel(float2* __restrict__ cs) {
  int idx = blockIdx.x * 256 + threadIdx.x;  // < 131072
  int pos = idx >> 6, i = idx & 63;
  float inv = powf(10000.0f, -(float)(2 * i) / 128.0f);
  float f = (float)pos * inv;
  cs[idx] = make_float2(cosf(f), sinf(f));
}

// ---------------- GEMM: C = A @ W^T ----------------
template <int MODE>
__global__ __launch_bounds__(256) void gemm_kernel(
    const bf16* __restrict__ A, const bf16* __restrict__ B0,
    const bf16* __restrict__ B1, const bf16* __restrict__ B2,
    bf16* __restrict__ Qh, bf16* __restrict__ Kh, bf16* __restrict__ VT,
    float* __restrict__ Cout, const int* __restrict__ positions,
    const float2* __restrict__ cs) {
  __shared__ __align__(16) bf16 As[128 * 32];
  __shared__ __align__(16) bf16 Bs[128 * 32];
  const int tid = threadIdx.x;
  const int lane = tid & 63;
  const int w = tid >> 6;
  const int wr = w >> 1, wc = w & 1;
  const int lr = lane & 15, lg = lane >> 4;
  const int brow = blockIdx.x * 128;
  const int bcol = blockIdx.y * 128;
  const int z = (MODE == 0) ? (int)blockIdx.z : 0;
  const bf16* Bt = (MODE == 1) ? B0 : (z == 0 ? B0 : (z == 1 ? B1 : B2));

  f32x4 acc[4][4];
#pragma unroll
  for (int m = 0; m < 4; ++m)
#pragma unroll
    for (int n = 0; n < 4; ++n) acc[m][n] = (f32x4){0.f, 0.f, 0.f, 0.f};

  for (int kt = 0; kt < DM / 32; ++kt) {
    __syncthreads();
#pragma unroll
    for (int p = 0; p < 2; ++p) {
      int slot = p * 256 + tid;
      int row = slot >> 2, kq = slot & 3;
      gload_lds16(A + (size_t)(brow + row) * DM + kt * 32 + kq * 8,
                  As + (size_t)(p * 256 + w * 64) * 8);
      gload_lds16(Bt + (size_t)(bcol + row) * DM + kt * 32 + kq * 8,
                  Bs + (size_t)(p * 256 + w * 64) * 8);
    }
    __syncthreads();
    bf16x8 afr[4], bfr[4];
#pragma unroll
    for (int m = 0; m < 4; ++m)
      afr[m] = *(const bf16x8*)(As + (wr * 64 + m * 16 + lr) * 32 + lg * 8);
#pragma unroll
    for (int n = 0; n < 4; ++n)
      bfr[n] = *(const bf16x8*)(Bs + (wc * 64 + n * 16 + lr) * 32 + lg * 8);
#pragma unroll
    for (int m = 0; m < 4; ++m)
#pragma unroll
      for (int n = 0; n < 4; ++n)
        acc[m][n] = __builtin_amdgcn_mfma_f32_16x16x32_bf16(afr[m], bfr[n],
                                                            acc[m][n], 0, 0, 0);
  }

  if (MODE == 1) {
#pragma unroll
    for (int m = 0; m < 4; ++m)
#pragma unroll
      for (int r = 0; r < 4; ++r) {
        int gr = brow + wr * 64 + m * 16 + lg * 4 + r;
#pragma unroll
        for (int n = 0; n < 4; ++n) {
          int j = bcol + wc * 64 + n * 16 + lr;
          Cout[(size_t)gr * DM + j] = acc[m][n][r];
        }
      }
  } else if (z < 2) {
    bf16* Dst = (z == 0) ? Qh : Kh;
#pragma unroll
    for (int m = 0; m < 4; ++m)
#pragma unroll
      for (int r = 0; r < 4; ++r) {
        int gr = brow + wr * 64 + m * 16 + lg * 4 + r;
        int b = gr >> 11, l = gr & (LL - 1);
        int pos = positions[gr];
#pragma unroll
        for (int n = 0; n < 4; ++n) {
          int j = bcol + wc * 64 + n * 16 + lr;
          float v = acc[m][n][r];
          float part = __shfl_xor(v, 1);
          int d = j & 127;
          float2 csv = cs[pos * 64 + (d >> 1)];
          float res = (j & 1) ? (part * csv.y + v * csv.x)
                              : (v * csv.x - part * csv.y);
          Dst[((size_t)(b * NH + (j >> 7)) * LL + l) * DH + d] = (bf16)res;
        }
      }
  } else {
    // V -> VT[bh][d][l]
#pragma unroll
    for (int m = 0; m < 4; ++m) {
      int gr0 = brow + wr * 64 + m * 16 + lg * 4;
      int b = gr0 >> 11, l0 = gr0 & (LL - 1);
#pragma unroll
      for (int n = 0; n < 4; ++n) {
        int j = bcol + wc * 64 + n * 16 + lr;
        int d = j & 127, h = j >> 7;
        bf16x4 o = {(bf16)acc[m][n][0], (bf16)acc[m][n][1], (bf16)acc[m][n][2],
                    (bf16)acc[m][n][3]};
        *(bf16x4*)(VT + ((size_t)(b * NH + h) * DH + d) * LL + l0) = o;
      }
    }
  }
}

// ---------------- causal flash attention ----------------
// 1D grid of 1024 blocks, XCD-pinned: each XCD owns 4 bh (K+V = 4MB = L2).
// block 256 = 4 waves; wave w owns 16 q rows; KVBLK=64; all LDS XOR-swizzled.
__global__ __launch_bounds__(256) void attn_kernel(const bf16* __restrict__ Qh,
                                                   const bf16* __restrict__ Kh,
                                                   const bf16* __restrict__ VT,
                                                   bf16* __restrict__ AO) {
  __shared__ __align__(16) bf16 Ks[64 * 128];
  __shared__ __align__(16) bf16 Vs[128 * 64];
  __shared__ __align__(16) bf16 Ps[4][16 * 64];
  const int tid = threadIdx.x;
  const int lane = tid & 63;
  const int w = tid >> 6;
  const int lr = lane & 15, lg = lane >> 4;
  // XCD-pinned mapping: bid%8 = xcd; 128 blocks/xcd = 4 bh x 32 qblocks
  const int bid = blockIdx.x;
  const int xcd = bid & 7;
  const int local = bid >> 3;
  const int bh = xcd * 4 + (local & 3);
  const int q0 = (local >> 2) * 64;
  const int qr0 = q0 + w * 16;
  const bf16* Qb = Qh + (size_t)bh * LL * DH;
  const bf16* Kb = Kh + (size_t)bh * LL * DH;
  const bf16* Vb = VT + (size_t)bh * DH * LL;

  bf16x8 qf[4];
#pragma unroll
  for (int dk = 0; dk < 4; ++dk)
    qf[dk] = *(const bf16x8*)(Qb + (size_t)(qr0 + lr) * DH + dk * 32 + lg * 8);

  float mx[4], ssum[4];
  f32x4 oacc[8];
#pragma unroll
  for (int r = 0; r < 4; ++r) {
    mx[r] = -1e30f;
    ssum[r] = 0.f;
  }
#pragma unroll
  for (int f = 0; f < 8; ++f) oacc[f] = (f32x4){0.f, 0.f, 0.f, 0.f};

  const float scale = 0.08838834764831845f;  // 1/sqrt(128)
  const int kvend = q0 + 64;
  for (int kv0 = 0; kv0 < kvend; kv0 += 64) {
    __syncthreads();
    // stage K tile [64][128], source-swizzled so LDS[row][c] = K[row][c^(row&7)]
#pragma unroll
    for (int rr = 0; rr < 4; ++rr) {
      int slot = rr * 256 + tid;
      int row = slot >> 4, c = slot & 15;
      gload_lds16(Kb + (size_t)(kv0 + row) * DH + ((c ^ (row & 7)) * 8),
                  Ks + (size_t)(rr * 256 + w * 64) * 8);
    }
    // stage V tile [128][64] (d-major), same swizzle on 16B chunks
#pragma unroll
    for (int rr = 0; rr < 4; ++rr) {
      int slot = rr * 256 + tid;
      int row = slot >> 3, c = slot & 7;
      gload_lds16(Vb + (size_t)row * LL + kv0 + ((c ^ (row & 7)) * 8),
                  Vs + (size_t)(rr * 256 + w * 64) * 8);
    }
    __syncthreads();
    if (kv0 <= qr0 + 15) {
      f32x4 s[4];
#pragma unroll
      for (int n = 0; n < 4; ++n) s[n] = (f32x4){0.f, 0.f, 0.f, 0.f};
#pragma unroll
      for (int n = 0; n < 4; ++n)
#pragma unroll
        for (int dk = 0; dk < 4; ++dk) {
          bf16x8 kf = *(const bf16x8*)(Ks + (n * 16 + lr) * 128 +
                                       (((dk * 4 + lg) ^ (lr & 7)) * 8));
          s[n] = __builtin_amdgcn_mfma_f32_16x16x32_bf16(qf[dk], kf, s[n], 0, 0, 0);
        }
      // causal mask (scores kept unscaled; scale folded into exp)
#pragma unroll
      for (int n = 0; n < 4; ++n)
#pragma unroll
        for (int r = 0; r < 4; ++r) {
          int c = kv0 + n * 16 + lr;
          int q = qr0 + lg * 4 + r;
          if (c > q) s[n][r] = -1e30f;
        }
      // per-row tile max + defer-max test (THR = 8 exp-units = 90.5 raw)
      float pm[4];
      bool ok = true;
#pragma unroll
      for (int r = 0; r < 4; ++r) {
        float tm = fmaxf(fmaxf(s[0][r], s[1][r]), fmaxf(s[2][r], s[3][r]));
        tm = fmaxf(tm, __shfl_xor(tm, 1));
        tm = fmaxf(tm, __shfl_xor(tm, 2));
        tm = fmaxf(tm, __shfl_xor(tm, 4));
        tm = fmaxf(tm, __shfl_xor(tm, 8));
        pm[r] = tm;
        ok = ok && (tm <= mx[r] + 90.0f);
      }
      if (!__all(ok)) {
        float al[4];
#pragma unroll
        for (int r = 0; r < 4; ++r) {
          float mn = fmaxf(mx[r], pm[r]);
          al[r] = __expf((mx[r] - mn) * scale);
          mx[r] = mn;
          ssum[r] *= al[r];
        }
#pragma unroll
        for (int f = 0; f < 8; ++f)
#pragma unroll
          for (int r = 0; r < 4; ++r) oacc[f][r] *= al[r];
      }
      // exp + row sum
#pragma unroll
      for (int r = 0; r < 4; ++r) {
        float t = 0.f;
#pragma unroll
        for (int n = 0; n < 4; ++n) {
          float e = __expf((s[n][r] - mx[r]) * scale);
          s[n][r] = e;
          t += e;
        }
        t += __shfl_xor(t, 1);
        t += __shfl_xor(t, 2);
        t += __shfl_xor(t, 4);
        t += __shfl_xor(t, 8);
        ssum[r] += t;
      }
      // P -> LDS (swizzled [16][64] per wave)
      bf16* pw = &Ps[w][0];
#pragma unroll
      for (int n = 0; n < 4; ++n)
#pragma unroll
        for (int r = 0; r < 4; ++r) {
          int row = lg * 4 + r;
          int ch = (n * 2 + (lr >> 3)) ^ (row & 7);
          pw[row * 64 + ch * 8 + (lr & 7)] = (bf16)s[n][r];
        }
      asm volatile("s_waitcnt lgkmcnt(0)" ::: "memory");
      __builtin_amdgcn_sched_barrier(0);
#pragma unroll
      for (int kt = 0; kt < 2; ++kt) {
        bf16x8 pf = *(const bf16x8*)(pw + lr * 64 +
                                     (((kt * 4 + lg) ^ (lr & 7)) * 8));
#pragma unroll
        for (int f = 0; f < 8; ++f) {
          bf16x8 vf = *(const bf16x8*)(Vs + (f * 16 + lr) * 64 +
                                       (((kt * 4 + lg) ^ (lr & 7)) * 8));
          oacc[f] = __builtin_amdgcn_mfma_f32_16x16x32_bf16(pf, vf, oacc[f], 0, 0, 0);
        }
      }
    }
  }
  const int b = bh >> 4, h = bh & 15;
#pragma unroll
  for (int f = 0; f < 8; ++f)
#pragma unroll
    for (int r = 0; r < 4; ++r) {
      int q = qr0 + lg * 4 + r;
      float val = oacc[f][r] / ssum[r];
      AO[((size_t)(b * LL + q)) * DM + h * DH + f * 16 + lr] = (bf16)val;
    }
}

extern "C" void kernel_launch(void* const* d_in, const int* in_sizes, int n_in,
                              void* d_out, int out_size, void* d_ws,
                              size_t ws_size, hipStream_t stream) {
  const float* x = (const float*)d_in[0];
  const int* positions = (const int*)d_in[1];
  const float* Wq = (const float*)d_in[2];
  const float* Wk = (const float*)d_in[3];
  const float* Wv = (const float*)d_in[4];
  const float* Wo = (const float*)d_in[5];
  float* out = (float*)d_out;
  char* ws = (char*)d_ws;
  const size_t MB = (size_t)1 << 20;
  bf16* xb = (bf16*)(ws + 0 * MB);     // 16 MB
  bf16* wqb = (bf16*)(ws + 16 * MB);   // 8 MB
  bf16* wkb = (bf16*)(ws + 24 * MB);   // 8 MB
  bf16* wvb = (bf16*)(ws + 32 * MB);   // 8 MB
  bf16* wob = (bf16*)(ws + 40 * MB);   // 8 MB
  bf16* Qh = (bf16*)(ws + 48 * MB);    // 16 MB
  bf16* Kh = (bf16*)(ws + 64 * MB);    // 16 MB
  bf16* VTb = (bf16*)(ws + 80 * MB);   // 16 MB
  bf16* AO = (bf16*)(ws + 96 * MB);    // 16 MB
  float2* cs = (float2*)(ws + 112 * MB);  // 1 MB

  convert_kernel<<<dim3(24576), dim3(256), 0, stream>>>(
      x, Wq, Wk, Wv, Wo, xb, wqb, wkb, wvb, wob);
  rope_table_kernel<<<dim3(512), dim3(256), 0, stream>>>(cs);
  gemm_kernel<0><<<dim3(32, 16, 3), dim3(256), 0, stream>>>(
      xb, wqb, wkb, wvb, Qh, Kh, VTb, nullptr, positions, cs);
  attn_kernel<<<dim3(1024), dim3(256), 0, stream>>>(Qh, Kh, VTb, AO);
  gemm_kernel<1><<<dim3(32, 16, 1), dim3(256), 0, stream>>>(
      AO, wob, nullptr, nullptr, nullptr, nullptr, nullptr, out, nullptr,
      nullptr);
}